// Round 1
// 42.798 us; speedup vs baseline: 1.0151x; 1.0151x over previous
//
#include <hip/hip_runtime.h>

#define NSEQ 2048   // B*S
#define TT 30       // T
#define DIN 500
#define NLAYER 64

// fast transcendentals: v_exp_f32 / v_rcp_f32 (~1 ulp rel err; threshold is 2% rel)
__device__ __forceinline__ float fexp(float x) {
    return __builtin_amdgcn_exp2f(x * 1.4426950408889634f);
}
__device__ __forceinline__ float fsigmoid(float x) {
    return __builtin_amdgcn_rcpf(1.0f + fexp(-x));
}
__device__ __forceinline__ float ftanh_(float x) {
    return fmaf(-2.0f, __builtin_amdgcn_rcpf(1.0f + fexp(2.0f * x)), 1.0f);
}
__device__ __forceinline__ float rdlane(float v, int l) {
    return __builtin_bit_cast(float, __builtin_amdgcn_readlane(__builtin_bit_cast(int, v), l));
}
// DPP cross-lane (2-cycle VALU, off the LDS pipe)
template <int CTRL>
__device__ __forceinline__ float dppmv(float v) {
    return __builtin_bit_cast(float, __builtin_amdgcn_update_dpp(
        0, __builtin_bit_cast(int, v), CTRL, 0xF, 0xF, false));
}
#define DPP_XOR1 0xB1   // quad_perm(1,0,3,2)
#define DPP_XOR2 0x4E   // quad_perm(2,3,0,1)
#define DPP_ROR4 0x124  // row_ror:4
#define DPP_ROR8 0x128  // row_ror:8
#define DPP_SHR1 0x138  // wave_shr:1 (lane l <- lane l-1)

// x float4 pairs with chunk-reversed weight float4: component c <-> component 3-c
__device__ __forceinline__ float dot4rev(const float4 xv, const float4 wv, float acc) {
    acc = fmaf(xv.x, wv.w, acc);
    acc = fmaf(xv.y, wv.z, acc);
    acc = fmaf(xv.z, wv.y, acc);
    acc = fmaf(xv.w, wv.x, acc);
    return acc;
}

// v2: ONE WAVE PER SEQUENCE (4 seqs/block, 512 blocks -> whole grid resident
// at 2 blocks/CU). Each wave runs its own phase 1 (30 t, double-buffered,
// lane-resident reversed weights, DPP row reduction) into a private 480 B LDS
// slice, then immediately its own phase-2 (layer,time) wavefront. No
// __syncthreads, no dead waves holding block slots: phase-2 VALU of finished
// waves overlaps phase-1 HBM streaming of the others for the whole kernel.
__global__ __launch_bounds__(256, 2) void fused_lstm(
    const float* __restrict__ x,       // (NSEQ, TT*DIN)
    const float* __restrict__ w_ih0,   // (4, DIN)
    const float* __restrict__ w_hh0,   // (4,1)
    const float* __restrict__ b_ih0,   // (4)
    const float* __restrict__ b_hh0,   // (4)
    const float* __restrict__ w_ih,    // (63,4,1)
    const float* __restrict__ w_hh,    // (63,4,1)
    const float* __restrict__ b_ih,    // (63,4)
    const float* __restrict__ b_hh,    // (63,4)
    float* __restrict__ out)           // (NSEQ, TT)
{
    __shared__ float pre[4][TT * 4];   // per-wave slice, 480 B each

    const int tid  = threadIdx.x;
    const int lane = tid & 63;
    const int w    = tid >> 6;
    const int n    = blockIdx.x * 4 + w;   // this wave's sequence
    const int s    = lane & 15;
    const int g    = lane >> 4;
    float* __restrict__ prew = pre[w];

    // ---- lane-resident chunk-reversed weights: 8 float4 = 32 VGPR ----
    const float4* __restrict__ w4 = (const float4*)w_ih0;   // 500 quads, row g = [g*125,+125)
    const float4 z4 = make_float4(0.f, 0.f, 0.f, 0.f);
    float4 wk[8];
#pragma unroll
    for (int k = 0; k < 8; ++k) {
        const int j = k * 16 + s;
        wk[k] = (j < 125) ? w4[g * 125 + (124 - j)] : z4;
    }

    const float4* __restrict__ xq = (const float4*)(x + (size_t)n * (TT * DIN));
    auto xload = [&](int t, float4 (&b)[8]) {
        const float4* __restrict__ p = xq + (TT - 1 - t) * 125;   // t in [0,29] always
#pragma unroll
        for (int k = 0; k < 8; ++k) {
            const int j = k * 16 + s;
            b[k] = p[(j < 125) ? j : 124];          // pad slices have zero weight
        }
    };
    auto compute = [&](const float4 (&b)[8], int t) {
        float a = 0.f;
#pragma unroll
        for (int k = 0; k < 8; ++k) a = dot4rev(b[k], wk[k], a);
        // 16-lane row sum, all DPP: quad xor1, xor2, then ror4, ror8
        a += dppmv<DPP_XOR1>(a);
        a += dppmv<DPP_XOR2>(a);
        a += dppmv<DPP_ROR4>(a);
        a += dppmv<DPP_ROR8>(a);
        if (s == 0) prew[t * 4 + g] = a;   // lanes 0,16,32,48: 4 consec floats
    };

    // ---- phase 1: this wave's 30 timesteps, double-buffered ----
    float4 A[8], B[8];
    xload(0, A);
#pragma unroll
    for (int t = 0; t < TT; t += 2) {      // TT even: handles t, t+1 per iter
        xload(t + 1, B);
        compute(A, t);
        if (t + 2 < TT) xload(t + 2, A);
        compute(B, t + 1);
    }
    // Same-wave DS ops retire in order; drain lgkm so the reads below see the
    // writes. "memory" clobber keeps the compiler from hoisting the ds_read.
    asm volatile("s_waitcnt lgkmcnt(0)" ::: "memory");

    // ---- phase-2 parameters ----
    float wih0 = 0.f, wih1 = 0.f, wih2 = 0.f, wih3 = 0.f;
    float whh0, whh1, whh2, whh3;
    float bia0 = 0.f, bia1 = 0.f, bia2 = 0.f, bia3 = 0.f;
    if (lane == 0) {
        whh0 = w_hh0[0]; whh1 = w_hh0[1]; whh2 = w_hh0[2]; whh3 = w_hh0[3];
    } else {
        const int l = lane - 1;
        wih0 = w_ih[l * 4 + 0]; wih1 = w_ih[l * 4 + 1];
        wih2 = w_ih[l * 4 + 2]; wih3 = w_ih[l * 4 + 3];
        whh0 = w_hh[l * 4 + 0]; whh1 = w_hh[l * 4 + 1];
        whh2 = w_hh[l * 4 + 2]; whh3 = w_hh[l * 4 + 3];
        bia0 = b_ih[l * 4 + 0] + b_hh[l * 4 + 0];
        bia1 = b_ih[l * 4 + 1] + b_hh[l * 4 + 1];
        bia2 = b_ih[l * 4 + 2] + b_hh[l * 4 + 2];
        bia3 = b_ih[l * 4 + 3] + b_hh[l * 4 + 3];
    }
    float pg0 = 0.f, pg1 = 0.f, pg2 = 0.f, pg3 = 0.f;
    if (lane < TT) {
        const float4 q = *(const float4*)&prew[lane * 4];
        pg0 = q.x + b_ih0[0] + b_hh0[0];
        pg1 = q.y + b_ih0[1] + b_hh0[1];
        pg2 = q.z + b_ih0[2] + b_hh0[2];
        pg3 = q.w + b_ih0[3] + b_hh0[3];
    }

    // ---- phase 2: (layer,time) wavefront, lane = layer ----
    float h = 0.f, c = 0.f;
    for (int k = 0; k < NLAYER + TT - 1; ++k) {
        const float h_in = dppmv<DPP_SHR1>(h);   // layer l-1's h at this lane's t
        const int t = k - lane;
        const bool active = (t >= 0) && (t < TT);

        float g0, g1, g2, g3;
        if (lane == 0) {
            g0 = g1 = g2 = g3 = 0.f;
        } else {
            g0 = fmaf(h_in, wih0, bia0);
            g1 = fmaf(h_in, wih1, bia1);
            g2 = fmaf(h_in, wih2, bia2);
            g3 = fmaf(h_in, wih3, bia3);
        }
        if (k < TT) {   // uniform: broadcast lane k's pre0 quad via SGPR
            const float p0 = rdlane(pg0, k);
            const float p1 = rdlane(pg1, k);
            const float p2 = rdlane(pg2, k);
            const float p3 = rdlane(pg3, k);
            if (lane == 0) { g0 = p0; g1 = p1; g2 = p2; g3 = p3; }
        }
        g0 = fmaf(h, whh0, g0);
        g1 = fmaf(h, whh1, g1);
        g2 = fmaf(h, whh2, g2);
        g3 = fmaf(h, whh3, g3);

        const float ig = fsigmoid(g0);
        const float fg = fsigmoid(g1);
        const float gg = ftanh_(g2);
        const float og = fsigmoid(g3);
        const float cn = fmaf(fg, c, ig * gg);
        const float hn = og * ftanh_(cn);

        if (active) { c = cn; h = hn; }
        if (lane == 63 && active) out[(size_t)n * TT + t] = hn;
    }
}

extern "C" void kernel_launch(void* const* d_in, const int* in_sizes, int n_in,
                              void* d_out, int out_size, void* d_ws, size_t ws_size,
                              hipStream_t stream) {
    const float* x     = (const float*)d_in[0];
    const float* w_ih0 = (const float*)d_in[1];
    const float* w_hh0 = (const float*)d_in[2];
    const float* b_ih0 = (const float*)d_in[3];
    const float* b_hh0 = (const float*)d_in[4];
    const float* w_ih  = (const float*)d_in[5];
    const float* w_hh  = (const float*)d_in[6];
    const float* b_ih  = (const float*)d_in[7];
    const float* b_hh  = (const float*)d_in[8];
    float* out = (float*)d_out;

    fused_lstm<<<NSEQ / 4, 256, 0, stream>>>(x, w_ih0, w_hh0, b_ih0, b_hh0,
                                             w_ih, w_hh, b_ih, b_hh, out);
}

// Round 2
// 42.114 us; speedup vs baseline: 1.0316x; 1.0163x over previous
//
#include <hip/hip_runtime.h>

#define NSEQ 2048   // B*S
#define TT 30       // T
#define DIN 500
#define NLAYER 64

// fast transcendentals: v_exp_f32 / v_rcp_f32 (~1 ulp rel err; threshold is 2% rel)
__device__ __forceinline__ float fexp(float x) {
    return __builtin_amdgcn_exp2f(x * 1.4426950408889634f);
}
__device__ __forceinline__ float fsigmoid(float x) {
    return __builtin_amdgcn_rcpf(1.0f + fexp(-x));
}
__device__ __forceinline__ float ftanh_(float x) {
    return fmaf(-2.0f, __builtin_amdgcn_rcpf(1.0f + fexp(2.0f * x)), 1.0f);
}
__device__ __forceinline__ float rdlane(float v, int l) {
    return __builtin_bit_cast(float, __builtin_amdgcn_readlane(__builtin_bit_cast(int, v), l));
}
// DPP cross-lane (2-cycle VALU, off the LDS pipe)
template <int CTRL>
__device__ __forceinline__ float dppmv(float v) {
    return __builtin_bit_cast(float, __builtin_amdgcn_update_dpp(
        0, __builtin_bit_cast(int, v), CTRL, 0xF, 0xF, false));
}
#define DPP_XOR1 0xB1   // quad_perm(1,0,3,2)
#define DPP_XOR2 0x4E   // quad_perm(2,3,0,1)
#define DPP_ROR4 0x124  // row_ror:4
#define DPP_ROR8 0x128  // row_ror:8
#define DPP_SHR1 0x138  // wave_shr:1 (lane l <- lane l-1)

// x float4 pairs with chunk-reversed weight float4: component c <-> component 3-c
__device__ __forceinline__ float dot4rev(const float4 xv, const float4 wv, float acc) {
    acc = fmaf(xv.x, wv.w, acc);
    acc = fmaf(xv.y, wv.z, acc);
    acc = fmaf(xv.z, wv.y, acc);
    acc = fmaf(xv.w, wv.x, acc);
    return acc;
}
// full 16-lane-row sum via DPP (row = 16 lanes; result in every lane of row)
__device__ __forceinline__ float red16(float a) {
    a += dppmv<DPP_XOR1>(a);
    a += dppmv<DPP_XOR2>(a);
    a += dppmv<DPP_ROR4>(a);
    a += dppmv<DPP_ROR8>(a);
    return a;
}

// v3: one wave per sequence (unchanged), but phase-1 is re-mapped so the four
// 16-lane groups own DIFFERENT timesteps (t = 4r + g) instead of different
// gates. Each lane holds all 4 gates' reversed weights for its slice column
// (32 float4 = 128 VGPR) -> per round of 4 t, the 8 x-loads are 64-lane
// DISTINCT (4x fewer load instrs + 4x less L1 return traffic than v2).
// The 128-VGPR weight array + sched_barrier(0) fences force the round-level
// double buffer to actually live in registers (v2 collapsed to 60 VGPR =
// no pipelining). Phase-2 params are issued at kernel top so their latency
// hides under phase 1.
__global__ __launch_bounds__(256, 2) void fused_lstm(
    const float* __restrict__ x,       // (NSEQ, TT*DIN)
    const float* __restrict__ w_ih0,   // (4, DIN)
    const float* __restrict__ w_hh0,   // (4,1)
    const float* __restrict__ b_ih0,   // (4)
    const float* __restrict__ b_hh0,   // (4)
    const float* __restrict__ w_ih,    // (63,4,1)
    const float* __restrict__ w_hh,    // (63,4,1)
    const float* __restrict__ b_ih,    // (63,4)
    const float* __restrict__ b_hh,    // (63,4)
    float* __restrict__ out)           // (NSEQ, TT)
{
    __shared__ float pre[4][TT * 4];   // per-wave slice, 480 B each

    const int tid  = threadIdx.x;
    const int lane = tid & 63;
    const int w    = tid >> 6;
    const int n    = blockIdx.x * 4 + w;   // this wave's sequence
    const int s    = lane & 15;
    const int g    = lane >> 4;
    float* __restrict__ prew = pre[w];

    // ---- issue phase-2 param loads NOW; consumed after phase 1 ----
    const int l = (lane == 0) ? 0 : (lane - 1);
    float4 wihv  = *(const float4*)(w_ih + l * 4);
    float4 whhv  = *(const float4*)(w_hh + l * 4);
    float4 bihv  = *(const float4*)(b_ih + l * 4);
    float4 bhhv  = *(const float4*)(b_hh + l * 4);
    float4 whh0v = *(const float4*)(w_hh0);
    float4 bi0v  = *(const float4*)(b_ih0);
    float4 bh0v  = *(const float4*)(b_hh0);
    __builtin_amdgcn_sched_barrier(0);   // pin issue before phase 1

    // ---- lane-resident chunk-reversed weights, ALL 4 gates: 32 float4 ----
    const float4* __restrict__ w4 = (const float4*)w_ih0;   // 500 quads, row gate*125
    const float4 z4 = make_float4(0.f, 0.f, 0.f, 0.f);
    float4 wk[4][8];
#pragma unroll
    for (int gate = 0; gate < 4; ++gate) {
#pragma unroll
        for (int k = 0; k < 8; ++k) {
            const int j = k * 16 + s;
            wk[gate][k] = (j < 125) ? w4[gate * 125 + (124 - j)] : z4;
        }
    }

    const float4* __restrict__ xq = (const float4*)(x + (size_t)n * (TT * DIN));
    // round r: group g loads timestep t = 4r + g (row 29-t), 16 lanes of the
    // group read 256 B contiguous per k; 64 lanes fully distinct.
    auto xround = [&](int r, float4 (&b)[8]) {
        const int t = r * 4 + g;
        int cc = TT - 1 - t; if (cc < 0) cc = 0;    // round 7, g>=2: clamped, unused
        const float4* __restrict__ p = xq + cc * 125;
#pragma unroll
        for (int k = 0; k < 8; ++k) {
            const int j = k * 16 + s;
            b[k] = p[(j < 125) ? j : 124];          // pad slices have zero weight
        }
    };
    auto cround = [&](const float4 (&b)[8], int r) {
        float a0 = 0.f, a1 = 0.f, a2 = 0.f, a3 = 0.f;
#pragma unroll
        for (int k = 0; k < 8; ++k) {
            a0 = dot4rev(b[k], wk[0][k], a0);
            a1 = dot4rev(b[k], wk[1][k], a1);
            a2 = dot4rev(b[k], wk[2][k], a2);
            a3 = dot4rev(b[k], wk[3][k], a3);
        }
        a0 = red16(a0); a1 = red16(a1); a2 = red16(a2); a3 = red16(a3);
        const int t = r * 4 + g;
        if (s == 0 && t < TT)
            *(float4*)&prew[t * 4] = make_float4(a0, a1, a2, a3);
    };

    // ---- phase 1: 8 rounds (30 t + 2 clamped), round-level double buffer ----
    float4 A[8], B[8];
    xround(0, A);
#pragma unroll
    for (int r = 0; r < 8; r += 2) {
        if (r + 1 < 8) xround(r + 1, B);
        __builtin_amdgcn_sched_barrier(0);   // loads issue before compute
        cround(A, r);
        if (r + 2 < 8) xround(r + 2, A);
        __builtin_amdgcn_sched_barrier(0);
        cround(B, r + 1);
    }
    // Same-wave DS ops retire in order; drain lgkm so the reads below see the
    // writes. "memory" clobber keeps the compiler from hoisting the ds_read.
    asm volatile("s_waitcnt lgkmcnt(0)" ::: "memory");

    // ---- phase-2 parameters (loads already in flight) ----
    float wih0, wih1, wih2, wih3, whh0, whh1, whh2, whh3;
    float bia0, bia1, bia2, bia3;
    if (lane == 0) {
        wih0 = wih1 = wih2 = wih3 = 0.f;
        bia0 = bia1 = bia2 = bia3 = 0.f;
        whh0 = whh0v.x; whh1 = whh0v.y; whh2 = whh0v.z; whh3 = whh0v.w;
    } else {
        wih0 = wihv.x; wih1 = wihv.y; wih2 = wihv.z; wih3 = wihv.w;
        whh0 = whhv.x; whh1 = whhv.y; whh2 = whhv.z; whh3 = whhv.w;
        bia0 = bihv.x + bhhv.x; bia1 = bihv.y + bhhv.y;
        bia2 = bihv.z + bhhv.z; bia3 = bihv.w + bhhv.w;
    }
    float pg0 = 0.f, pg1 = 0.f, pg2 = 0.f, pg3 = 0.f;
    if (lane < TT) {
        const float4 q = *(const float4*)&prew[lane * 4];
        pg0 = q.x + bi0v.x + bh0v.x;
        pg1 = q.y + bi0v.y + bh0v.y;
        pg2 = q.z + bi0v.z + bh0v.z;
        pg3 = q.w + bi0v.w + bh0v.w;
    }

    // ---- phase 2: (layer,time) wavefront, lane = layer ----
    float h = 0.f, c = 0.f;
    for (int k = 0; k < NLAYER + TT - 1; ++k) {
        const float h_in = dppmv<DPP_SHR1>(h);   // layer l-1's h at this lane's t
        const int t = k - lane;
        const bool active = (t >= 0) && (t < TT);

        float g0, g1, g2, g3;
        if (lane == 0) {
            g0 = g1 = g2 = g3 = 0.f;
        } else {
            g0 = fmaf(h_in, wih0, bia0);
            g1 = fmaf(h_in, wih1, bia1);
            g2 = fmaf(h_in, wih2, bia2);
            g3 = fmaf(h_in, wih3, bia3);
        }
        if (k < TT) {   // uniform: broadcast lane k's pre0 quad via SGPR
            const float p0 = rdlane(pg0, k);
            const float p1 = rdlane(pg1, k);
            const float p2 = rdlane(pg2, k);
            const float p3 = rdlane(pg3, k);
            if (lane == 0) { g0 = p0; g1 = p1; g2 = p2; g3 = p3; }
        }
        g0 = fmaf(h, whh0, g0);
        g1 = fmaf(h, whh1, g1);
        g2 = fmaf(h, whh2, g2);
        g3 = fmaf(h, whh3, g3);

        const float ig = fsigmoid(g0);
        const float fg = fsigmoid(g1);
        const float gg = ftanh_(g2);
        const float og = fsigmoid(g3);
        const float cn = fmaf(fg, c, ig * gg);
        const float hn = og * ftanh_(cn);

        if (active) { c = cn; h = hn; }
        if (lane == 63 && active) out[(size_t)n * TT + t] = hn;
    }
}

extern "C" void kernel_launch(void* const* d_in, const int* in_sizes, int n_in,
                              void* d_out, int out_size, void* d_ws, size_t ws_size,
                              hipStream_t stream) {
    const float* x     = (const float*)d_in[0];
    const float* w_ih0 = (const float*)d_in[1];
    const float* w_hh0 = (const float*)d_in[2];
    const float* b_ih0 = (const float*)d_in[3];
    const float* b_hh0 = (const float*)d_in[4];
    const float* w_ih  = (const float*)d_in[5];
    const float* w_hh  = (const float*)d_in[6];
    const float* b_ih  = (const float*)d_in[7];
    const float* b_hh  = (const float*)d_in[8];
    float* out = (float*)d_out;

    fused_lstm<<<NSEQ / 4, 256, 0, stream>>>(x, w_ih0, w_hh0, b_ih0, b_hh0,
                                             w_ih, w_hh, b_ih, b_hh, out);
}